// Round 1
// baseline (292.246 us; speedup 1.0000x reference)
//
#include <hip/hip_runtime.h>

#define VV 8
#define JJ 64
#define THR 400.0f
#define ALPHA 0.1f

__global__ void zero_out_kernel(float* out) { out[0] = 0.0f; }

__global__ __launch_bounds__(256) void proj_loss_kernel(
    const float* __restrict__ kps_gt,    // [B,J,3]
    const float* __restrict__ kps_pred,  // [B,J,3]
    const float* __restrict__ gt_R,      // [B,V,3,3]
    const float* __restrict__ gt_t,      // [B,V,3]
    const float* __restrict__ Kmat,      // [V,3,3]
    const float* __restrict__ cam,       // [B,V,3,4]
    float* __restrict__ out,
    float scale)                         // 1/(2*B)
{
    __shared__ float s_gt[JJ * 3];
    __shared__ float s_pr[JJ * 3];
    __shared__ float s_R[VV * 9];
    __shared__ float s_t[VV * 3];
    __shared__ float s_C[VV * 12];
    __shared__ float s_K[VV * 9];
    __shared__ float s_red[4];

    const int b = blockIdx.x;
    const int tid = threadIdx.x;

    const float* gbase = kps_gt + (size_t)b * (JJ * 3);
    const float* pbase = kps_pred + (size_t)b * (JJ * 3);
    const float* Rbase = gt_R + (size_t)b * (VV * 9);
    const float* tbase = gt_t + (size_t)b * (VV * 3);
    const float* cbase = cam + (size_t)b * (VV * 12);

    if (tid < JJ * 3) { s_gt[tid] = gbase[tid]; s_pr[tid] = pbase[tid]; }
    if (tid < VV * 9) { s_R[tid] = Rbase[tid]; s_K[tid] = Kmat[tid]; }
    if (tid < VV * 3) s_t[tid] = tbase[tid];
    if (tid < VV * 12) s_C[tid] = cbase[tid];
    __syncthreads();

    const float c09 = powf(THR, 0.9f);  // compile-time folded

    float acc = 0.0f;
#pragma unroll
    for (int it = 0; it < 2; ++it) {
        const int p = tid + it * 256;   // p in [0, 512)
        const int v = p >> 6;
        const int j = p & 63;

        const float X0 = s_gt[3 * j + 0];
        const float X1 = s_gt[3 * j + 1];
        const float X2 = s_gt[3 * j + 2];
        const float* R = &s_R[9 * v];
        const float* tv = &s_t[3 * v];
        const float Xc0 = R[0] * X0 + R[1] * X1 + R[2] * X2 + tv[0];
        const float Xc1 = R[3] * X0 + R[4] * X1 + R[5] * X2 + tv[1];
        const float Xc2 = R[6] * X0 + R[7] * X1 + R[8] * X2 + tv[2];

        const float* Kv = &s_K[9 * v];
        const float x0 = Kv[0] * Xc0 + Kv[1] * Xc1 + Kv[2] * Xc2;
        const float x1 = Kv[3] * Xc0 + Kv[4] * Xc1 + Kv[5] * Xc2;
        const float x2 = Kv[6] * Xc0 + Kv[7] * Xc1 + Kv[8] * Xc2;
        const float g0 = x0 / x2;
        const float g1 = x1 / x2;

        const float P0 = s_pr[3 * j + 0];
        const float P1 = s_pr[3 * j + 1];
        const float P2 = s_pr[3 * j + 2];
        const float* C = &s_C[12 * v];
        const float Y0 = C[0] * P0 + C[1] * P1 + C[2] * P2 + C[3];
        const float Y1 = C[4] * P0 + C[5] * P1 + C[6] * P2 + C[7];
        const float Y2 = C[8] * P0 + C[9] * P1 + C[10] * P2 + C[11];
        const float y0 = Kv[0] * Y0 + Kv[1] * Y1 + Kv[2] * Y2;
        const float y1 = Kv[3] * Y0 + Kv[4] * Y1 + Kv[5] * Y2;
        const float y2 = Kv[6] * Y0 + Kv[7] * Y1 + Kv[8] * Y2;
        const float q0 = y0 / y2;
        const float q1 = y1 / y2;

        float d0 = g0 - q0; d0 *= d0;
        float d1 = g1 - q1; d1 *= d1;
        d0 = (d0 > THR) ? powf(d0, ALPHA) * c09 : d0;
        d1 = (d1 > THR) ? powf(d1, ALPHA) * c09 : d1;
        acc += d0 + d1;
    }

    // wave-64 reduction
#pragma unroll
    for (int off = 32; off > 0; off >>= 1)
        acc += __shfl_down(acc, off, 64);

    const int wave = tid >> 6;
    const int lane = tid & 63;
    if (lane == 0) s_red[wave] = acc;
    __syncthreads();
    if (tid == 0) {
        const float s = s_red[0] + s_red[1] + s_red[2] + s_red[3];
        atomicAdd(out, s * scale);
    }
}

extern "C" void kernel_launch(void* const* d_in, const int* in_sizes, int n_in,
                              void* d_out, int out_size, void* d_ws, size_t ws_size,
                              hipStream_t stream) {
    const float* kps_gt   = (const float*)d_in[0];
    const float* kps_pred = (const float*)d_in[1];
    const float* gt_R     = (const float*)d_in[2];
    const float* gt_t     = (const float*)d_in[3];
    const float* Kmat     = (const float*)d_in[4];
    const float* cam      = (const float*)d_in[5];
    float* out = (float*)d_out;

    const int B = in_sizes[0] / (JJ * 3);  // 16384
    const float scale = 1.0f / (2.0f * (float)B);

    zero_out_kernel<<<1, 1, 0, stream>>>(out);
    proj_loss_kernel<<<B, 256, 0, stream>>>(kps_gt, kps_pred, gt_R, gt_t, Kmat,
                                            cam, out, scale);
}

// Round 2
// 157.809 us; speedup vs baseline: 1.8519x; 1.8519x over previous
//
#include <hip/hip_runtime.h>

#define VV 8
#define JJ 64
#define THR 400.0f
#define ALPHA 0.1f
#define NBLOCKS 2048

__global__ __launch_bounds__(256) void proj_loss_kernel(
    const float* __restrict__ kps_gt,    // [B,J,3]
    const float* __restrict__ kps_pred,  // [B,J,3]
    const float* __restrict__ gt_R,      // [B,V,3,3]
    const float* __restrict__ gt_t,      // [B,V,3]
    const float* __restrict__ Kmat,      // [V,3,3]
    const float* __restrict__ cam,       // [B,V,3,4]
    float* __restrict__ partials,        // [NBLOCKS]
    int B)
{
    __shared__ float s_gt[JJ * 3];
    __shared__ float s_pr[JJ * 3];
    __shared__ float s_R[VV * 9];
    __shared__ float s_t[VV * 3];
    __shared__ float s_C[VV * 12];
    __shared__ float s_K[VV * 9];
    __shared__ float s_red[4];

    const int tid = threadIdx.x;

    if (tid < VV * 9) s_K[tid] = Kmat[tid];

    const float c09 = powf(THR, 0.9f);  // compile-time folded

    float acc = 0.0f;

    for (int b = blockIdx.x; b < B; b += NBLOCKS) {
        const float* gbase = kps_gt + (size_t)b * (JJ * 3);
        const float* pbase = kps_pred + (size_t)b * (JJ * 3);
        const float* Rbase = gt_R + (size_t)b * (VV * 9);
        const float* tbase = gt_t + (size_t)b * (VV * 3);
        const float* cbase = cam + (size_t)b * (VV * 12);

        __syncthreads();  // protect LDS from previous iteration's readers
        if (tid < JJ * 3) { s_gt[tid] = gbase[tid]; s_pr[tid] = pbase[tid]; }
        if (tid < VV * 9) s_R[tid] = Rbase[tid];
        if (tid < VV * 3) s_t[tid] = tbase[tid];
        if (tid < VV * 12) s_C[tid] = cbase[tid];
        __syncthreads();

#pragma unroll
        for (int it = 0; it < 2; ++it) {
            const int p = tid + it * 256;   // p in [0, 512)
            const int v = p >> 6;
            const int j = p & 63;

            const float X0 = s_gt[3 * j + 0];
            const float X1 = s_gt[3 * j + 1];
            const float X2 = s_gt[3 * j + 2];
            const float* R = &s_R[9 * v];
            const float* tv = &s_t[3 * v];
            const float Xc0 = R[0] * X0 + R[1] * X1 + R[2] * X2 + tv[0];
            const float Xc1 = R[3] * X0 + R[4] * X1 + R[5] * X2 + tv[1];
            const float Xc2 = R[6] * X0 + R[7] * X1 + R[8] * X2 + tv[2];

            const float* Kv = &s_K[9 * v];
            const float x0 = Kv[0] * Xc0 + Kv[1] * Xc1 + Kv[2] * Xc2;
            const float x1 = Kv[3] * Xc0 + Kv[4] * Xc1 + Kv[5] * Xc2;
            const float x2 = Kv[6] * Xc0 + Kv[7] * Xc1 + Kv[8] * Xc2;
            const float rg = __builtin_amdgcn_rcpf(x2);
            const float g0 = x0 * rg;
            const float g1 = x1 * rg;

            const float P0 = s_pr[3 * j + 0];
            const float P1 = s_pr[3 * j + 1];
            const float P2 = s_pr[3 * j + 2];
            const float* C = &s_C[12 * v];
            const float Y0 = C[0] * P0 + C[1] * P1 + C[2] * P2 + C[3];
            const float Y1 = C[4] * P0 + C[5] * P1 + C[6] * P2 + C[7];
            const float Y2 = C[8] * P0 + C[9] * P1 + C[10] * P2 + C[11];
            const float y0 = Kv[0] * Y0 + Kv[1] * Y1 + Kv[2] * Y2;
            const float y1 = Kv[3] * Y0 + Kv[4] * Y1 + Kv[5] * Y2;
            const float y2 = Kv[6] * Y0 + Kv[7] * Y1 + Kv[8] * Y2;
            const float rp = __builtin_amdgcn_rcpf(y2);
            const float q0 = y0 * rp;
            const float q1 = y1 * rp;

            float d0 = g0 - q0; d0 *= d0;
            float d1 = g1 - q1; d1 *= d1;
            d0 = (d0 > THR) ? powf(d0, ALPHA) * c09 : d0;
            d1 = (d1 > THR) ? powf(d1, ALPHA) * c09 : d1;
            acc += d0 + d1;
        }
    }

    // wave-64 reduction
#pragma unroll
    for (int off = 32; off > 0; off >>= 1)
        acc += __shfl_down(acc, off, 64);

    const int wave = tid >> 6;
    const int lane = tid & 63;
    if (lane == 0) s_red[wave] = acc;
    __syncthreads();
    if (tid == 0)
        partials[blockIdx.x] = s_red[0] + s_red[1] + s_red[2] + s_red[3];
}

__global__ __launch_bounds__(256) void reduce_kernel(
    const float* __restrict__ partials, float* __restrict__ out, float scale)
{
    __shared__ float s_red[4];
    const int tid = threadIdx.x;
    float acc = 0.0f;
#pragma unroll
    for (int i = 0; i < NBLOCKS / 256; ++i)
        acc += partials[tid + i * 256];
#pragma unroll
    for (int off = 32; off > 0; off >>= 1)
        acc += __shfl_down(acc, off, 64);
    const int wave = tid >> 6;
    const int lane = tid & 63;
    if (lane == 0) s_red[wave] = acc;
    __syncthreads();
    if (tid == 0)
        out[0] = (s_red[0] + s_red[1] + s_red[2] + s_red[3]) * scale;
}

extern "C" void kernel_launch(void* const* d_in, const int* in_sizes, int n_in,
                              void* d_out, int out_size, void* d_ws, size_t ws_size,
                              hipStream_t stream) {
    const float* kps_gt   = (const float*)d_in[0];
    const float* kps_pred = (const float*)d_in[1];
    const float* gt_R     = (const float*)d_in[2];
    const float* gt_t     = (const float*)d_in[3];
    const float* Kmat     = (const float*)d_in[4];
    const float* cam      = (const float*)d_in[5];
    float* out = (float*)d_out;
    float* partials = (float*)d_ws;

    const int B = in_sizes[0] / (JJ * 3);  // 16384
    const float scale = 1.0f / (2.0f * (float)B);

    proj_loss_kernel<<<NBLOCKS, 256, 0, stream>>>(kps_gt, kps_pred, gt_R, gt_t,
                                                  Kmat, cam, partials, B);
    reduce_kernel<<<1, 256, 0, stream>>>(partials, out, scale);
}

// Round 4
// 108.182 us; speedup vs baseline: 2.7014x; 1.4587x over previous
//
#include <hip/hip_runtime.h>

#define VV 8
#define JJ 64
#define THR 400.0f
#define ALPHA 0.1f
#define NBLOCKS 2048

__global__ __launch_bounds__(256) void proj_loss_kernel(
    const float* __restrict__ kps_gt,    // [B,J,3]
    const float* __restrict__ kps_pred,  // [B,J,3]
    const float* __restrict__ gt_R,      // [B,V,3,3]
    const float* __restrict__ gt_t,      // [B,V,3]
    const float* __restrict__ Kmat,      // [V,3,3]
    const float* __restrict__ cam,       // [B,V,3,4]
    float* __restrict__ partials,        // [NBLOCKS]
    int B)
{
    __shared__ float s_gt[JJ * 3];
    __shared__ float s_pr[JJ * 3];
    __shared__ float s_R[VV * 9];
    __shared__ float s_t[VV * 3];
    __shared__ float s_C[VV * 12];
    __shared__ float s_K[VV * 9];
    __shared__ float4 s_M[VV * 3];   // M[v] = K@[R|t], rows as float4
    __shared__ float4 s_N[VV * 3];   // N[v] = K@C,     rows as float4
    __shared__ float s_red[4];

    const int tid = threadIdx.x;
    const int lane = tid & 63;
    const int wave = tid >> 6;

    if (tid < VV * 9) s_K[tid] = Kmat[tid];

    const float c09 = powf(THR, 0.9f);  // compile-time constant

    float acc = 0.0f;

    for (int b = blockIdx.x; b < B; b += NBLOCKS) {
        const float* gbase = kps_gt + (size_t)b * (JJ * 3);
        const float* pbase = kps_pred + (size_t)b * (JJ * 3);
        const float* Rbase = gt_R + (size_t)b * (VV * 9);
        const float* tbase = gt_t + (size_t)b * (VV * 3);
        const float* cbase = cam + (size_t)b * (VV * 12);

        __syncthreads();  // protect LDS from previous iteration's readers
        if (tid < JJ * 3) { s_gt[tid] = gbase[tid]; s_pr[tid] = pbase[tid]; }
        if (tid < VV * 9) s_R[tid] = Rbase[tid];
        if (tid < VV * 3) s_t[tid] = tbase[tid];
        if (tid < VV * 12) s_C[tid] = cbase[tid];
        __syncthreads();

        // Fold intrinsics: M[v] = K[v] @ [R[v] | t[v]],  N[v] = K[v] @ C[v].
        // 192 entries, one per thread (tid < 192).
        if (tid < 192) {
            const int which = (tid >= 96) ? 1 : 0;
            const int e = which ? tid - 96 : tid;
            const int v = e / 12;
            const int idx = e - v * 12;
            const int r = idx >> 2;
            const int c = idx & 3;
            const float* Kv = &s_K[9 * v];
            const float k0 = Kv[3 * r + 0];
            const float k1 = Kv[3 * r + 1];
            const float k2 = Kv[3 * r + 2];
            float a0, a1, a2;
            if (which) {                       // N = K @ C  (C is [3][4])
                const float* C = &s_C[12 * v];
                a0 = C[c]; a1 = C[4 + c]; a2 = C[8 + c];
            } else if (c < 3) {                // M cols 0..2 = K @ R
                const float* R = &s_R[9 * v];
                a0 = R[c]; a1 = R[3 + c]; a2 = R[6 + c];
            } else {                           // M col 3 = K @ t
                const float* t = &s_t[3 * v];
                a0 = t[0]; a1 = t[1]; a2 = t[2];
            }
            const float val = fmaf(k0, a0, fmaf(k1, a1, k2 * a2));
            float* dst = which ? (float*)s_N : (float*)s_M;
            dst[v * 12 + r * 4 + c] = val;
        }
        __syncthreads();

        // Per-lane keypoint (j = lane), reused across both v iterations.
        const float X0 = s_gt[3 * lane + 0];
        const float X1 = s_gt[3 * lane + 1];
        const float X2 = s_gt[3 * lane + 2];
        const float P0 = s_pr[3 * lane + 0];
        const float P1 = s_pr[3 * lane + 1];
        const float P2 = s_pr[3 * lane + 2];

#pragma unroll
        for (int it = 0; it < 2; ++it) {
            const int v = wave + it * 4;   // wave-uniform view index

            const float4 M0 = s_M[v * 3 + 0];
            const float4 M1 = s_M[v * 3 + 1];
            const float4 M2 = s_M[v * 3 + 2];
            const float x0 = fmaf(M0.x, X0, fmaf(M0.y, X1, fmaf(M0.z, X2, M0.w)));
            const float x1 = fmaf(M1.x, X0, fmaf(M1.y, X1, fmaf(M1.z, X2, M1.w)));
            const float x2 = fmaf(M2.x, X0, fmaf(M2.y, X1, fmaf(M2.z, X2, M2.w)));
            const float rg = __builtin_amdgcn_rcpf(x2);
            const float g0 = x0 * rg;
            const float g1 = x1 * rg;

            const float4 N0 = s_N[v * 3 + 0];
            const float4 N1 = s_N[v * 3 + 1];
            const float4 N2 = s_N[v * 3 + 2];
            const float y0 = fmaf(N0.x, P0, fmaf(N0.y, P1, fmaf(N0.z, P2, N0.w)));
            const float y1 = fmaf(N1.x, P0, fmaf(N1.y, P1, fmaf(N1.z, P2, N1.w)));
            const float y2 = fmaf(N2.x, P0, fmaf(N2.y, P1, fmaf(N2.z, P2, N2.w)));
            const float rp = __builtin_amdgcn_rcpf(y2);
            const float q0 = y0 * rp;
            const float q1 = y1 * rp;

            float d0 = g0 - q0; d0 *= d0;
            float d1 = g1 - q1; d1 *= d1;
            // d^0.1 * 400^0.9 via hardware log2/exp2:
            //   v_log_f32 = log2(x), v_exp_f32 = 2^x  =>  2^(0.1*log2 d) = d^0.1
            if (d0 > THR) d0 = __builtin_amdgcn_exp2f(ALPHA * __builtin_amdgcn_logf(d0)) * c09;
            if (d1 > THR) d1 = __builtin_amdgcn_exp2f(ALPHA * __builtin_amdgcn_logf(d1)) * c09;
            acc += d0 + d1;
        }
    }

    // wave-64 reduction
#pragma unroll
    for (int off = 32; off > 0; off >>= 1)
        acc += __shfl_down(acc, off, 64);

    if (lane == 0) s_red[wave] = acc;
    __syncthreads();
    if (tid == 0)
        partials[blockIdx.x] = s_red[0] + s_red[1] + s_red[2] + s_red[3];
}

__global__ __launch_bounds__(256) void reduce_kernel(
    const float* __restrict__ partials, float* __restrict__ out, float scale)
{
    __shared__ float s_red[4];
    const int tid = threadIdx.x;
    float acc = 0.0f;
#pragma unroll
    for (int i = 0; i < NBLOCKS / 256; ++i)
        acc += partials[tid + i * 256];
#pragma unroll
    for (int off = 32; off > 0; off >>= 1)
        acc += __shfl_down(acc, off, 64);
    const int wave = tid >> 6;
    const int lane = tid & 63;
    if (lane == 0) s_red[wave] = acc;
    __syncthreads();
    if (tid == 0)
        out[0] = (s_red[0] + s_red[1] + s_red[2] + s_red[3]) * scale;
}

extern "C" void kernel_launch(void* const* d_in, const int* in_sizes, int n_in,
                              void* d_out, int out_size, void* d_ws, size_t ws_size,
                              hipStream_t stream) {
    const float* kps_gt   = (const float*)d_in[0];
    const float* kps_pred = (const float*)d_in[1];
    const float* gt_R     = (const float*)d_in[2];
    const float* gt_t     = (const float*)d_in[3];
    const float* Kmat     = (const float*)d_in[4];
    const float* cam      = (const float*)d_in[5];
    float* out = (float*)d_out;
    float* partials = (float*)d_ws;

    const int B = in_sizes[0] / (JJ * 3);  // 16384
    const float scale = 1.0f / (2.0f * (float)B);

    proj_loss_kernel<<<NBLOCKS, 256, 0, stream>>>(kps_gt, kps_pred, gt_R, gt_t,
                                                  Kmat, cam, partials, B);
    reduce_kernel<<<1, 256, 0, stream>>>(partials, out, scale);
}

// Round 5
// 105.175 us; speedup vs baseline: 2.7787x; 1.0286x over previous
//
#include <hip/hip_runtime.h>

#define VV 8
#define JJ 64
#define THR 400.0f
#define ALPHA 0.1f

// ---------------------------------------------------------------------------
// Kernel 1: fold intrinsics into per-(b,v) projection matrices.
//   M[b,v] = K[v] @ [R[b,v] | t[b,v]]   (3x4)
//   N[b,v] = K[v] @ C[b,v]              (3x4)
// Output layout: MN[(b*V+v)*6 + which*3 + r] as float4 rows.
// One thread per row: B*V*6 = 786432 rows.
// ---------------------------------------------------------------------------
__global__ __launch_bounds__(256) void fold_kernel(
    const float* __restrict__ gt_R,   // [B,V,3,3]
    const float* __restrict__ gt_t,   // [B,V,3]
    const float* __restrict__ Kmat,   // [V,3,3]
    const float* __restrict__ cam,    // [B,V,3,4]
    float4* __restrict__ MN,
    int nrows)
{
    const int row = blockIdx.x * 256 + threadIdx.x;
    if (row >= nrows) return;
    const int r = row % 3;
    const int which = (row / 3) & 1;
    const int bv = row / 6;
    const int v = bv & (VV - 1);

    const float* Kv = Kmat + v * 9 + r * 3;
    const float k0 = Kv[0], k1 = Kv[1], k2 = Kv[2];

    float4 o;
    if (which == 0) {
        const float* R = gt_R + (size_t)bv * 9;
        const float* t = gt_t + (size_t)bv * 3;
        o.x = fmaf(k0, R[0], fmaf(k1, R[3], k2 * R[6]));
        o.y = fmaf(k0, R[1], fmaf(k1, R[4], k2 * R[7]));
        o.z = fmaf(k0, R[2], fmaf(k1, R[5], k2 * R[8]));
        o.w = fmaf(k0, t[0], fmaf(k1, t[1], k2 * t[2]));
    } else {
        const float4* C = (const float4*)(cam + (size_t)bv * 12);
        const float4 c0 = C[0], c1 = C[1], c2 = C[2];
        o.x = fmaf(k0, c0.x, fmaf(k1, c1.x, k2 * c2.x));
        o.y = fmaf(k0, c0.y, fmaf(k1, c1.y, k2 * c2.y));
        o.z = fmaf(k0, c0.z, fmaf(k1, c1.z, k2 * c2.z));
        o.w = fmaf(k0, c0.w, fmaf(k1, c1.w, k2 * c2.w));
    }
    MN[row] = o;
}

// ---------------------------------------------------------------------------
// Kernel 2: loss. One wave per batch element, lane = keypoint j.
// No LDS staging, no barriers in the hot path. M/N rows are wave-uniform
// (readfirstlane-forced) -> scalar s_load path, broadcast to lanes.
// ---------------------------------------------------------------------------
__global__ __launch_bounds__(256) void loss_kernel(
    const float* __restrict__ kps_gt,    // [B,J,3]
    const float* __restrict__ kps_pred,  // [B,J,3]
    const float4* __restrict__ MN,       // [B*V*6]
    float* __restrict__ partials)        // [B/4]
{
    __shared__ float s_red[4];
    const int tid = threadIdx.x;
    const int lane = tid & 63;
    const int wave = tid >> 6;
    const int b = __builtin_amdgcn_readfirstlane(blockIdx.x * 4 + wave);

    const float* g = kps_gt + (size_t)b * (JJ * 3) + lane * 3;
    const float X0 = g[0], X1 = g[1], X2 = g[2];
    const float* p = kps_pred + (size_t)b * (JJ * 3) + lane * 3;
    const float P0 = p[0], P1 = p[1], P2 = p[2];

    const float4* mn = MN + (size_t)b * (VV * 6);
    const float c09 = powf(THR, 0.9f);  // compile-time constant

    float acc = 0.0f;
#pragma unroll
    for (int v = 0; v < VV; ++v) {
        const float4 M0 = mn[v * 6 + 0];
        const float4 M1 = mn[v * 6 + 1];
        const float4 M2 = mn[v * 6 + 2];
        const float4 N0 = mn[v * 6 + 3];
        const float4 N1 = mn[v * 6 + 4];
        const float4 N2 = mn[v * 6 + 5];

        const float x0 = fmaf(M0.x, X0, fmaf(M0.y, X1, fmaf(M0.z, X2, M0.w)));
        const float x1 = fmaf(M1.x, X0, fmaf(M1.y, X1, fmaf(M1.z, X2, M1.w)));
        const float x2 = fmaf(M2.x, X0, fmaf(M2.y, X1, fmaf(M2.z, X2, M2.w)));
        const float rg = __builtin_amdgcn_rcpf(x2);
        const float g0 = x0 * rg;
        const float g1 = x1 * rg;

        const float y0 = fmaf(N0.x, P0, fmaf(N0.y, P1, fmaf(N0.z, P2, N0.w)));
        const float y1 = fmaf(N1.x, P0, fmaf(N1.y, P1, fmaf(N1.z, P2, N1.w)));
        const float y2 = fmaf(N2.x, P0, fmaf(N2.y, P1, fmaf(N2.z, P2, N2.w)));
        const float rp = __builtin_amdgcn_rcpf(y2);
        const float q0 = y0 * rp;
        const float q1 = y1 * rp;

        float d0 = g0 - q0; d0 *= d0;
        float d1 = g1 - q1; d1 *= d1;
        // d^0.1 * 400^0.9 via v_log_f32 (log2) + v_exp_f32 (2^x)
        if (d0 > THR) d0 = __builtin_amdgcn_exp2f(ALPHA * __builtin_amdgcn_logf(d0)) * c09;
        if (d1 > THR) d1 = __builtin_amdgcn_exp2f(ALPHA * __builtin_amdgcn_logf(d1)) * c09;
        acc += d0 + d1;
    }

#pragma unroll
    for (int off = 32; off > 0; off >>= 1)
        acc += __shfl_down(acc, off, 64);

    if (lane == 0) s_red[wave] = acc;
    __syncthreads();
    if (tid == 0)
        partials[blockIdx.x] = s_red[0] + s_red[1] + s_red[2] + s_red[3];
}

// ---------------------------------------------------------------------------
// Kernel 3: final reduction of 4096 partials.
// ---------------------------------------------------------------------------
__global__ __launch_bounds__(256) void reduce_kernel(
    const float* __restrict__ partials, float* __restrict__ out,
    float scale, int n)
{
    __shared__ float s_red[4];
    const int tid = threadIdx.x;
    float acc = 0.0f;
    for (int i = tid; i < n; i += 256)
        acc += partials[i];
#pragma unroll
    for (int off = 32; off > 0; off >>= 1)
        acc += __shfl_down(acc, off, 64);
    const int wave = tid >> 6;
    const int lane = tid & 63;
    if (lane == 0) s_red[wave] = acc;
    __syncthreads();
    if (tid == 0)
        out[0] = (s_red[0] + s_red[1] + s_red[2] + s_red[3]) * scale;
}

extern "C" void kernel_launch(void* const* d_in, const int* in_sizes, int n_in,
                              void* d_out, int out_size, void* d_ws, size_t ws_size,
                              hipStream_t stream) {
    const float* kps_gt   = (const float*)d_in[0];
    const float* kps_pred = (const float*)d_in[1];
    const float* gt_R     = (const float*)d_in[2];
    const float* gt_t     = (const float*)d_in[3];
    const float* Kmat     = (const float*)d_in[4];
    const float* cam      = (const float*)d_in[5];
    float* out = (float*)d_out;

    const int B = in_sizes[0] / (JJ * 3);  // 16384
    const float scale = 1.0f / (2.0f * (float)B);

    float4* MN = (float4*)d_ws;                       // B*V*6 float4 = 12.6 MB
    float* partials = (float*)((char*)d_ws + (size_t)B * VV * 6 * sizeof(float4));

    const int nrows = B * VV * 6;                     // 786432
    fold_kernel<<<(nrows + 255) / 256, 256, 0, stream>>>(gt_R, gt_t, Kmat, cam,
                                                         MN, nrows);
    loss_kernel<<<B / 4, 256, 0, stream>>>(kps_gt, kps_pred, MN, partials);
    reduce_kernel<<<1, 256, 0, stream>>>(partials, out, scale, B / 4);
}